// Round 3
// baseline (243.365 us; speedup 1.0000x reference)
//
#include <hip/hip_runtime.h>
#include <hip/hip_bf16.h>
#include <stdint.h>

#define IN_F   4096
#define OUT_F  4096
#define M_ROWS 2048
#define NG     32
#define GRP    128

typedef int   v4i  __attribute__((ext_vector_type(4)));
typedef float f32x4 __attribute__((ext_vector_type(4)));

typedef const void __attribute__((address_space(1))) cv_g;
typedef void       __attribute__((address_space(3))) v_l;

__device__ __forceinline__ void async16(const void* g, void* l) {
  // global -> LDS DMA, 16B/lane; LDS dest = wave-uniform base + lane*16.
  __builtin_amdgcn_global_load_lds((cv_g*)g, (v_l*)l, 16, 0, 0);
}

// perm dtype flag (fallback path only): 1 if int64, 0 if int32.
__device__ int g_perm_is64;

__global__ void decode_flag(const void* __restrict__ perm_raw) {
  if (threadIdx.x == 0 && blockIdx.x == 0) {
    const int* w = (const int*)perm_raw;
    int ok = 1;
    for (int j = 0; j < 32; ++j) {
      int lo = w[2 * j], hi = w[2 * j + 1];
      if (hi != 0 || lo < 0 || lo >= IN_F) { ok = 0; break; }
    }
    g_perm_is64 = ok;
  }
}

// Fused preprocessing (int8 edition) -- unchanged from verified version.
__global__ __launch_bounds__(256) void prep(const float* __restrict__ x,
                                            const int* __restrict__ w_q,
                                            const void* __restrict__ perm_raw,
                                            char* __restrict__ xq,
                                            char* __restrict__ w8,
                                            float* __restrict__ sxr) {
  __shared__ float sx[IN_F];
  __shared__ float red[4];
  __shared__ int sflag;
  const int b = blockIdx.x;
  const int t = threadIdx.x;

  if (b < M_ROWS) {
    const int m = b;
    const float* xr = x + (size_t)m * IN_F;
#pragma unroll
    for (int u = 0; u < 4; ++u) {
      int idx = (u * 256 + t) * 4;
      *(float4*)&sx[idx] = *(const float4*)&xr[idx];
    }
    if (t < 64) {
      const int* w = (const int*)perm_raw;
      int j = t & 31;
      int lo = w[2 * j], hi = w[2 * j + 1];
      int cond = (hi == 0 && lo >= 0 && lo < IN_F);
      unsigned long long bal = __ballot(cond);
      if (t == 0) sflag = (bal == ~0ull) ? 1 : 0;
    }
    __syncthreads();
    const int f = sflag;
    const long long* p64 = (const long long*)perm_raw;
    const int*       p32 = (const int*)perm_raw;
    const int jb = t * 16;
    float vals[16];
    float lmax = 0.f;
#pragma unroll
    for (int u = 0; u < 16; ++u) {
      int pj = f ? (int)p64[jb + u] : p32[jb + u];
      float v = sx[pj];
      vals[u] = v;
      lmax = fmaxf(lmax, fabsf(v));
    }
#pragma unroll
    for (int d = 1; d < 64; d <<= 1)
      lmax = fmaxf(lmax, __shfl_xor(lmax, d, 64));
    if ((t & 63) == 0) red[t >> 6] = lmax;
    __syncthreads();
    float rmax = fmaxf(fmaxf(red[0], red[1]), fmaxf(red[2], red[3]));
    float inv = (rmax > 0.f) ? 127.f / rmax : 0.f;
    if (t == 0) sxr[m] = rmax / 127.f;
    char q[16] __attribute__((aligned(16)));
#pragma unroll
    for (int u = 0; u < 16; ++u)
      q[u] = (char)__float2int_rn(vals[u] * inv);
    *(uint4*)(xq + (size_t)m * IN_F + jb) = *(const uint4*)q;
  } else {
    const int o  = b - M_ROWS;
    const int kb = t * 16;
    const int* wr = w_q + (size_t)o * IN_F + kb;
    int4 w0 = *(const int4*)(wr + 0);
    int4 w1 = *(const int4*)(wr + 4);
    int4 w2 = *(const int4*)(wr + 8);
    int4 w3 = *(const int4*)(wr + 12);
    char q[16] __attribute__((aligned(16)));
    q[0]=(char)w0.x; q[1]=(char)w0.y; q[2]=(char)w0.z; q[3]=(char)w0.w;
    q[4]=(char)w1.x; q[5]=(char)w1.y; q[6]=(char)w1.z; q[7]=(char)w1.w;
    q[8]=(char)w2.x; q[9]=(char)w2.y; q[10]=(char)w2.z; q[11]=(char)w2.w;
    q[12]=(char)w3.x; q[13]=(char)w3.y; q[14]=(char)w3.z; q[15]=(char)w3.w;
    *(uint4*)(w8 + (size_t)o * IN_F + kb) = *(const uint4*)q;
  }
}

// C[m,o] = sxr[m] * sum_g s_w[g,o] * (int8 dot over group g) + bias[o]
//
// R11: B bypasses LDS entirely. A B-fragment for mfma_i32_16x16x64_i8 is 16
// contiguous K-bytes per lane -> a global_load_dwordx4 from w8 delivers the
// exact bytes the old LDS path produced (16 rows x 64B lines, coalesced,
// L1/L2-served: per-CU B working set is 32KB/tile, and the two wm-waves of a
// block read identical B rows -> L1 hits). Effects vs the 56us baseline:
//  - LDS traffic/CU-tile: 192KB -> 96KB (A reads 64K + A DMA writes 32K);
//    LDS leaves the critical path (i8 MFMA needs 2x the fragment bytes of
//    bf16 per MFMA-cycle -- LDS was the most-loaded pipe).
//  - counted vmcnt: per tile each thread issues 4 A-DMAs then 8 B-loads
//    (order pinned by sched_barrier(0)); tile-end "s_waitcnt vmcnt(8)" waits
//    exactly the 4 A-DMAs (FIFO, m135) while B stays in flight across the
//    barrier. B for tile t+1 prefetched during tile t (~1300cy compute >>
//    worst-case ~900cy HBM latency).
//  - registers: accf 64 + bf_cur/bf_next 64 + acci 16 + af 8 transient
//    ~= 210 peak < 256 (2 waves/SIMD cap). NO 16-entry offset tables (the
//    R10 spill: WRITE_SIZE 33->68MB).
// A staging keeps the verified R0 16B-chunk XOR geometry (reads 2-way-
// aliased, free). LDS: sws 8K | bufA0 16K | bufA1 16K = 40KB, 2 blocks/CU.
__global__ __launch_bounds__(256, 2) void gemm_i8(
    const char* __restrict__ A,     // xq  M x K int8
    const char* __restrict__ B,     // w8  N x K int8
    const float* __restrict__ s_w,  // NG x OUT_F
    const float* __restrict__ sxr,  // M
    const float* __restrict__ bias,
    float* __restrict__ C) {
  __shared__ __attribute__((aligned(16))) char lds[40960];
  unsigned short* sws = (unsigned short*)lds;  // [NG][128] bf16
  const int BUF0 = 8192, BUF1 = 24576;

  const int tid  = threadIdx.x;
  const int wave = tid >> 6;
  const int lane = tid & 63;
  const int bm = blockIdx.y << 7;
  const int bn = blockIdx.x << 7;
  const int wm = (wave >> 1) << 6;
  const int wn = (wave & 1) << 6;
  const int lrow = lane & 15;
  const int quad = lane >> 4;

  // stage s_w block into LDS as bf16 (K-loop stays free of scalar global)
#pragma unroll
  for (int u = 0; u < 16; ++u) {
    int idx = u * 256 + tid;  // 4096 entries: [g][c]
    int g = idx >> 7, c = idx & 127;
    __hip_bfloat16 h = __float2bfloat16(s_w[(size_t)g * OUT_F + bn + c]);
    sws[idx] = *(unsigned short*)&h;
  }

  // A staging descriptors (verified R0 geometry, A half only): 4 rounds x
  // 64 lanes = 1024 chunks of 16B per 16KB tile. chunk c: row=c>>3,
  // kc=(c&7)^(row&7); LDS offset c*16.
  const char* gp[4];
  int lofs[4];
#pragma unroll
  for (int h = 0; h < 4; ++h) {
    int c0 = (h * 4 + wave) * 64;
    int c  = c0 + lane;
    int row = c >> 3;
    int kc  = (c & 7) ^ (row & 7);
    gp[h]   = A + (size_t)(bm + row) * IN_F + kc * 16;
    lofs[h] = c0 * 16;
  }

  f32x4 accf[4][4] = {};
  v4i   acci[4][4] = {};
  v4i   bfX[2][4], bfY[2][4];

  auto rescale = [&](int g) {
    float swv[4];
#pragma unroll
    for (int j = 0; j < 4; ++j) {
      unsigned int u = sws[g * 128 + wn + j * 16 + lrow];
      swv[j] = __uint_as_float(u << 16);
    }
#pragma unroll
    for (int i = 0; i < 4; ++i)
#pragma unroll
      for (int j = 0; j < 4; ++j) {
#pragma unroll
        for (int r = 0; r < 4; ++r)
          accf[i][j][r] += swv[j] * (float)acci[i][j][r];
        acci[i][j] = (v4i){0, 0, 0, 0};
      }
  };

  // B fragment address: row = bn+wn+j*16+lrow, 16B at k = T*128+(s*4+quad)*16.
  const char* Brow = B + (size_t)(bn + wn + lrow) * IN_F + (quad << 4);

  // TILE(T): A frags from PB (staged last tile), B frags from BC (prefetched
  // last tile); stage A(T+1)->QB, prefetch B(T+1)->BN_; rescale group T-1 in
  // the load shadow; 32 MFMAs; counted vmcnt + barrier.
#define TILE(T, PB, QB, BC, BN_, DOPREV, DOSTAGE)                              \
  {                                                                            \
    if (DOSTAGE) {                                                             \
      const int kn = (T + 1) * GRP;                                            \
      _Pragma("unroll")                                                        \
      for (int h = 0; h < 4; ++h) async16(gp[h] + kn, &lds[QB + lofs[h]]);     \
      __builtin_amdgcn_sched_barrier(0);                                       \
      _Pragma("unroll")                                                        \
      for (int s = 0; s < 2; ++s)                                              \
        _Pragma("unroll")                                                      \
        for (int j = 0; j < 4; ++j)                                            \
          BN_[s][j] = *(const v4i*)(Brow + (size_t)(j * 16) * IN_F +           \
                                    (T + 1) * GRP + (s << 6));                 \
      __builtin_amdgcn_sched_barrier(0);                                       \
    }                                                                          \
    if (DOPREV) rescale((T) - 1);                                              \
    _Pragma("unroll")                                                          \
    for (int s = 0; s < 2; ++s) {                                              \
      v4i af[4];                                                               \
      _Pragma("unroll")                                                        \
      for (int i = 0; i < 4; ++i) {                                            \
        int row = wm + i * 16 + lrow;                                          \
        af[i] = *(const v4i*)&lds[PB + row * 128 +                             \
                                  ((((s << 2) | quad) ^ (lrow & 7)) << 4)];    \
      }                                                                        \
      __builtin_amdgcn_s_setprio(1);                                           \
      _Pragma("unroll")                                                        \
      for (int i = 0; i < 4; ++i)                                              \
        _Pragma("unroll")                                                      \
        for (int j = 0; j < 4; ++j)                                            \
          acci[i][j] = __builtin_amdgcn_mfma_i32_16x16x64_i8(                  \
              af[i], BC[s][j], acci[i][j], 0, 0, 0);                           \
      __builtin_amdgcn_s_setprio(0);                                           \
    }                                                                          \
    if (DOSTAGE) {                                                             \
      asm volatile("s_waitcnt vmcnt(8)" ::: "memory");                         \
      __builtin_amdgcn_s_barrier();                                            \
      asm volatile("" ::: "memory");                                           \
    }                                                                          \
  }

  // prologue: A tile0 -> BUF0 (4 DMA), then B tile0 -> bfX (8 loads);
  // vmcnt(8) waits exactly the A DMAs; lgkmcnt(0) drains sws ds_writes.
#pragma unroll
  for (int h = 0; h < 4; ++h) async16(gp[h], &lds[BUF0 + lofs[h]]);
  __builtin_amdgcn_sched_barrier(0);
#pragma unroll
  for (int s = 0; s < 2; ++s)
#pragma unroll
    for (int j = 0; j < 4; ++j)
      bfX[s][j] = *(const v4i*)(Brow + (size_t)(j * 16) * IN_F + (s << 6));
  __builtin_amdgcn_sched_barrier(0);
  asm volatile("s_waitcnt vmcnt(8) lgkmcnt(0)" ::: "memory");
  __builtin_amdgcn_s_barrier();
  asm volatile("" ::: "memory");

  for (int it = 0; it < 16; ++it) {
    TILE(2 * it,     BUF0, BUF1, bfX, bfY, (it > 0), true);
    TILE(2 * it + 1, BUF1, BUF0, bfY, bfX, true,     (it < 15));
  }
  rescale(NG - 1);
#undef TILE

  // Epilogue: C/D layout col=lane&15, row=quad*4+reg (dtype-independent).
#pragma unroll
  for (int i = 0; i < 4; ++i) {
    int r0 = bm + wm + i * 16 + quad * 4;
    float sxv[4];
#pragma unroll
    for (int r = 0; r < 4; ++r) sxv[r] = sxr[r0 + r];
#pragma unroll
    for (int j = 0; j < 4; ++j) {
      int col = bn + wn + j * 16 + lrow;
      float bv = bias[col];
#pragma unroll
      for (int r = 0; r < 4; ++r)
        C[(size_t)(r0 + r) * OUT_F + col] = sxv[r] * accf[i][j][r] + bv;
    }
  }
}

// Correct-but-slow fp32 fallback if workspace is too small.
__global__ void naive_fallback(const float* __restrict__ x, const int* __restrict__ w_q,
                               const float* __restrict__ s_w, const void* __restrict__ perm_raw,
                               const float* __restrict__ bias, float* __restrict__ out) {
  int t = blockIdx.x * blockDim.x + threadIdx.x;
  int m = t >> 12;
  int o = t & 4095;
  const int f = g_perm_is64;
  const long long* p64 = (const long long*)perm_raw;
  const int*       p32 = (const int*)perm_raw;
  const float* xr = x + (size_t)m * IN_F;
  const int*   wr = w_q + (size_t)o * IN_F;
  float acc = 0.f;
  for (int g = 0; g < NG; ++g) {
    float part = 0.f;
    for (int k = 0; k < GRP; ++k) {
      int j = g * GRP + k;
      int pj = f ? (int)p64[j] : p32[j];
      part += xr[pj] * (float)wr[j];
    }
    acc += part * s_w[(size_t)g * OUT_F + o];
  }
  out[t] = acc + bias[o];
}

extern "C" void kernel_launch(void* const* d_in, const int* in_sizes, int n_in,
                              void* d_out, int out_size, void* d_ws, size_t ws_size,
                              hipStream_t stream) {
  const float* x    = (const float*)d_in[0];
  const int*   w_q  = (const int*)d_in[1];
  const float* s_w  = (const float*)d_in[2];
  const void*  perm = d_in[3];   // int64 or int32 -- detected on device
  const float* bias = (const float*)d_in[4];
  float* out = (float*)d_out;

  const size_t xq_bytes = (size_t)M_ROWS * IN_F;            // 8 MiB int8
  const size_t w8_bytes = (size_t)OUT_F * IN_F;             // 16 MiB int8
  const size_t sx_bytes = (size_t)M_ROWS * sizeof(float);   // 8 KiB
  const size_t need = xq_bytes + w8_bytes + sx_bytes;

  if (ws_size < need) {
    decode_flag<<<1, 64, 0, stream>>>(perm);
    naive_fallback<<<(M_ROWS * OUT_F) / 256, 256, 0, stream>>>(x, w_q, s_w, perm, bias, out);
    return;
  }

  char*  xq  = (char*)d_ws;
  char*  w8  = (char*)d_ws + xq_bytes;
  float* sxr = (float*)((char*)d_ws + xq_bytes + w8_bytes);

  prep<<<M_ROWS + OUT_F, 256, 0, stream>>>(x, w_q, perm, xq, w8, sxr);

  dim3 grid(OUT_F / 128, M_ROWS / 128);  // 32 x 16 = 512 blocks, 2/CU
  gemm_i8<<<grid, 256, 0, stream>>>(xq, w8, s_w, sxr, bias, out);
}

// Round 4
// 217.976 us; speedup vs baseline: 1.1165x; 1.1165x over previous
//
#include <hip/hip_runtime.h>
#include <hip/hip_bf16.h>
#include <stdint.h>

#define IN_F   4096
#define OUT_F  4096
#define M_ROWS 2048
#define NG     32
#define GRP    128

typedef int   v4i  __attribute__((ext_vector_type(4)));
typedef float f32x4 __attribute__((ext_vector_type(4)));

typedef const void __attribute__((address_space(1))) cv_g;
typedef void       __attribute__((address_space(3))) v_l;

__device__ __forceinline__ void async16(const void* g, void* l) {
  // global -> LDS DMA, 16B/lane; LDS dest = wave-uniform base + lane*16.
  __builtin_amdgcn_global_load_lds((cv_g*)g, (v_l*)l, 16, 0, 0);
}

// perm dtype flag (fallback path only): 1 if int64, 0 if int32.
__device__ int g_perm_is64;

__global__ void decode_flag(const void* __restrict__ perm_raw) {
  if (threadIdx.x == 0 && blockIdx.x == 0) {
    const int* w = (const int*)perm_raw;
    int ok = 1;
    for (int j = 0; j < 32; ++j) {
      int lo = w[2 * j], hi = w[2 * j + 1];
      if (hi != 0 || lo < 0 || lo >= IN_F) { ok = 0; break; }
    }
    g_perm_is64 = ok;
  }
}

// Fused preprocessing (int8 edition) -- unchanged from verified version.
__global__ __launch_bounds__(256) void prep(const float* __restrict__ x,
                                            const int* __restrict__ w_q,
                                            const void* __restrict__ perm_raw,
                                            char* __restrict__ xq,
                                            char* __restrict__ w8,
                                            float* __restrict__ sxr) {
  __shared__ float sx[IN_F];
  __shared__ float red[4];
  __shared__ int sflag;
  const int b = blockIdx.x;
  const int t = threadIdx.x;

  if (b < M_ROWS) {
    const int m = b;
    const float* xr = x + (size_t)m * IN_F;
#pragma unroll
    for (int u = 0; u < 4; ++u) {
      int idx = (u * 256 + t) * 4;
      *(float4*)&sx[idx] = *(const float4*)&xr[idx];
    }
    if (t < 64) {
      const int* w = (const int*)perm_raw;
      int j = t & 31;
      int lo = w[2 * j], hi = w[2 * j + 1];
      int cond = (hi == 0 && lo >= 0 && lo < IN_F);
      unsigned long long bal = __ballot(cond);
      if (t == 0) sflag = (bal == ~0ull) ? 1 : 0;
    }
    __syncthreads();
    const int f = sflag;
    const long long* p64 = (const long long*)perm_raw;
    const int*       p32 = (const int*)perm_raw;
    const int jb = t * 16;
    float vals[16];
    float lmax = 0.f;
#pragma unroll
    for (int u = 0; u < 16; ++u) {
      int pj = f ? (int)p64[jb + u] : p32[jb + u];
      float v = sx[pj];
      vals[u] = v;
      lmax = fmaxf(lmax, fabsf(v));
    }
#pragma unroll
    for (int d = 1; d < 64; d <<= 1)
      lmax = fmaxf(lmax, __shfl_xor(lmax, d, 64));
    if ((t & 63) == 0) red[t >> 6] = lmax;
    __syncthreads();
    float rmax = fmaxf(fmaxf(red[0], red[1]), fmaxf(red[2], red[3]));
    float inv = (rmax > 0.f) ? 127.f / rmax : 0.f;
    if (t == 0) sxr[m] = rmax / 127.f;
    char q[16] __attribute__((aligned(16)));
#pragma unroll
    for (int u = 0; u < 16; ++u)
      q[u] = (char)__float2int_rn(vals[u] * inv);
    *(uint4*)(xq + (size_t)m * IN_F + jb) = *(const uint4*)q;
  } else {
    const int o  = b - M_ROWS;
    const int kb = t * 16;
    const int* wr = w_q + (size_t)o * IN_F + kb;
    int4 w0 = *(const int4*)(wr + 0);
    int4 w1 = *(const int4*)(wr + 4);
    int4 w2 = *(const int4*)(wr + 8);
    int4 w3 = *(const int4*)(wr + 12);
    char q[16] __attribute__((aligned(16)));
    q[0]=(char)w0.x; q[1]=(char)w0.y; q[2]=(char)w0.z; q[3]=(char)w0.w;
    q[4]=(char)w1.x; q[5]=(char)w1.y; q[6]=(char)w1.z; q[7]=(char)w1.w;
    q[8]=(char)w2.x; q[9]=(char)w2.y; q[10]=(char)w2.z; q[11]=(char)w2.w;
    q[12]=(char)w3.x; q[13]=(char)w3.y; q[14]=(char)w3.z; q[15]=(char)w3.w;
    *(uint4*)(w8 + (size_t)o * IN_F + kb) = *(const uint4*)q;
  }
}

// C[m,o] = sxr[m] * sum_g s_w[g,o] * (int8 dot over group g) + bias[o]
//
// R12: A streams global->VGPR (an A-fragment for mfma_i32_16x16x64_i8 is 16
// contiguous K-bytes per lane: A[row][t*128 + s*64 + quad*16], row =
// wm+i*16+lrow -- the exact bytes the old LDS path delivered). Pipelined at
// K-SLICE granularity: afC/afN = 32 regs only (R10/R11 died spilling on
// 64-reg tile-granular double buffers; acci[4][4] alone is 64 regs).
// B keeps the verified XOR DMA staging (double-buffered 16KB x2 + sws 8K =
// 40KB LDS, 2 blocks/CU). LDS traffic per CU-tile halves: 192KB -> 96KB,
// dropping LDS below the MFMA floor (the binding pipe at 56us: ~4MB frag
// reads + 2MB DMA writes per CU ~= 50-75Kcyc vs MFMA 41.8Kcyc).
//
// vmcnt-FIFO discipline (issue order pinned by sched_barrier(0)):
//   afN(t,s1) -> B-DMA(t+1) -> [slice-0 MFMA] -> afC(t+1,s0) ->
//   [slice-1 MFMA] -> rescale(t) -> vmcnt(4) -> s_barrier
// Pre-barrier outstanding = B-DMA(4, oldest) + afC-prefetch(4): vmcnt(4)
// drains exactly the B-DMA (publishable at the barrier) and keeps the A
// prefetch in flight across it. Compiler-inserted waits for the plain A
// loads count the newer loads only (FIFO), so B never drains mid-tile.
// acci zero-init via zero-C on the slice-0 MFMAs (kills 64 movs/tile).
// Live regs ~= accf 64 + acci 64 + afC/afN 32 + bf 16 + bases ~30 = ~206.
__global__ __launch_bounds__(256, 2) void gemm_i8(
    const char* __restrict__ A,     // xq  M x K int8
    const char* __restrict__ B,     // w8  N x K int8
    const float* __restrict__ s_w,  // NG x OUT_F
    const float* __restrict__ sxr,  // M
    const float* __restrict__ bias,
    float* __restrict__ C) {
  __shared__ __attribute__((aligned(16))) char lds[40960];
  unsigned short* sws = (unsigned short*)lds;  // [NG][128] bf16
  const int BUF0 = 8192, BUF1 = 24576;

  const int tid  = threadIdx.x;
  const int wave = tid >> 6;
  const int lane = tid & 63;
  const int bm = blockIdx.y << 7;
  const int bn = blockIdx.x << 7;
  const int wm = (wave >> 1) << 6;
  const int wn = (wave & 1) << 6;
  const int lrow = lane & 15;
  const int quad = lane >> 4;
  const int xlo  = lrow & 7;

  // stage s_w block into LDS as bf16 (K-loop stays free of scalar global)
#pragma unroll
  for (int u = 0; u < 16; ++u) {
    int idx = u * 256 + tid;  // 4096 entries: [g][c]
    int g = idx >> 7, c = idx & 127;
    __hip_bfloat16 h = __float2bfloat16(s_w[(size_t)g * OUT_F + bn + c]);
    sws[idx] = *(unsigned short*)&h;
  }

  // B staging (verified XOR geometry, B half only): 1024 16B chunks/tile.
  // chunk c = h*256 + wave*64 + lane: row = h*32 + wave*8 + (lane>>3),
  // kc = (lane&7)^(lane>>3) (h,wave drop out of row&7). Single base pointer;
  // h-terms are compile-time multiples under unroll.
  const char* gB = B + (size_t)(bn + wave * 8 + (lane >> 3)) * IN_F +
                   (((lane & 7) ^ (lane >> 3)) << 4);
  const int lB = wave * 1024;  // + h*4096 (compile-time) within buffer

  // A row base: lane(lrow,quad) of wave row-block wm reads rows wm+i*16+lrow,
  // 16B at k = t*128 + s*64 + quad*16. i-term = i*16*IN_F, compile-time.
  const char* gA = A + (size_t)(bm + wm + lrow) * IN_F + (quad << 4);

  f32x4 accf[4][4] = {};
  const v4i zero4 = {0, 0, 0, 0};

  // prologue: B(0) DMA, then A(0,s0) prefetch; vmcnt(4) retires the DMA
  // (oldest 4) and keeps the A loads flying; lgkmcnt(0) publishes sws.
#pragma unroll
  for (int h = 0; h < 4; ++h)
    async16(gB + (size_t)h * (32 * IN_F), &lds[BUF0 + lB + h * 4096]);
  __builtin_amdgcn_sched_barrier(0);
  v4i afC[4], afN[4];
#pragma unroll
  for (int i = 0; i < 4; ++i)
    afC[i] = *(const v4i*)(gA + (size_t)i * (16 * IN_F));
  asm volatile("s_waitcnt vmcnt(4) lgkmcnt(0)" ::: "memory");
  __builtin_amdgcn_s_barrier();
  asm volatile("" ::: "memory");

  for (int t = 0; t < NG; ++t) {
    const int p = t & 1;
    const char* bufB = &lds[p ? BUF1 : BUF0];
    char* stgB = &lds[p ? BUF0 : BUF1];
    const int kt = t * GRP;

    // A(t,s1) prefetch FIRST (so the compiler's wait for it never has to
    // retire the B-DMA issued just after), then B-DMA(t+1). Order pinned.
#pragma unroll
    for (int i = 0; i < 4; ++i)
      afN[i] = *(const v4i*)(gA + (size_t)i * (16 * IN_F) + kt + 64);
    __builtin_amdgcn_sched_barrier(0);
    if (t + 1 < NG) {
#pragma unroll
      for (int h = 0; h < 4; ++h)
        async16(gB + (size_t)h * (32 * IN_F) + kt + GRP,
                stgB + lB + h * 4096);
    }
    __builtin_amdgcn_sched_barrier(0);

    v4i acci[4][4];
    {  // slice 0 (k = kt..kt+64): zero-C MFMAs start the group
      v4i bf[4];
#pragma unroll
      for (int j = 0; j < 4; ++j)
        bf[j] = *(const v4i*)&bufB[(wn + j * 16 + lrow) * 128 +
                                   ((quad ^ xlo) << 4)];
      __builtin_amdgcn_s_setprio(1);
#pragma unroll
      for (int i = 0; i < 4; ++i)
#pragma unroll
        for (int j = 0; j < 4; ++j)
          acci[i][j] = __builtin_amdgcn_mfma_i32_16x16x64_i8(
              afC[i], bf[j], zero4, 0, 0, 0);
      __builtin_amdgcn_s_setprio(0);
    }

    // A(t+1,s0) prefetch into afC (its regs are dead after slice-0 issue)
    if (t + 1 < NG) {
#pragma unroll
      for (int i = 0; i < 4; ++i)
        afC[i] = *(const v4i*)(gA + (size_t)i * (16 * IN_F) + kt + GRP);
    }

    {  // slice 1 (k = kt+64..kt+128)
      v4i bf[4];
#pragma unroll
      for (int j = 0; j < 4; ++j)
        bf[j] = *(const v4i*)&bufB[(wn + j * 16 + lrow) * 128 +
                                   (((4 | quad) ^ xlo) << 4)];
      __builtin_amdgcn_s_setprio(1);
#pragma unroll
      for (int i = 0; i < 4; ++i)
#pragma unroll
        for (int j = 0; j < 4; ++j)
          acci[i][j] = __builtin_amdgcn_mfma_i32_16x16x64_i8(
              afN[i], bf[j], acci[i][j], 0, 0, 0);
      __builtin_amdgcn_s_setprio(0);
    }

    // per-group rescale (exact int32 -> f32, scaled by s_w[g, col])
    {
      float swv[4];
#pragma unroll
      for (int j = 0; j < 4; ++j) {
        unsigned int u = sws[t * 128 + wn + j * 16 + lrow];
        swv[j] = __uint_as_float(u << 16);
      }
#pragma unroll
      for (int i = 0; i < 4; ++i)
#pragma unroll
        for (int j = 0; j < 4; ++j)
#pragma unroll
          for (int r = 0; r < 4; ++r)
            accf[i][j][r] += swv[j] * (float)acci[i][j][r];
    }

    // tile-end: drain exactly the B-DMA (oldest 4 of {B-DMA, afC-prefetch}),
    // publish at the barrier; A prefetch stays in flight across it.
    if (t + 1 < NG) {
      asm volatile("s_waitcnt vmcnt(4)" ::: "memory");
      __builtin_amdgcn_s_barrier();
      asm volatile("" ::: "memory");
    }
  }

  // Epilogue: C/D layout col=lane&15, row=quad*4+reg (dtype-independent).
#pragma unroll
  for (int i = 0; i < 4; ++i) {
    int r0 = bm + wm + i * 16 + quad * 4;
    float sxv[4];
#pragma unroll
    for (int r = 0; r < 4; ++r) sxv[r] = sxr[r0 + r];
#pragma unroll
    for (int j = 0; j < 4; ++j) {
      int col = bn + wn + j * 16 + lrow;
      float bv = bias[col];
#pragma unroll
      for (int r = 0; r < 4; ++r)
        C[(size_t)(r0 + r) * OUT_F + col] = sxv[r] * accf[i][j][r] + bv;
    }
  }
}

// Correct-but-slow fp32 fallback if workspace is too small.
__global__ void naive_fallback(const float* __restrict__ x, const int* __restrict__ w_q,
                               const float* __restrict__ s_w, const void* __restrict__ perm_raw,
                               const float* __restrict__ bias, float* __restrict__ out) {
  int t = blockIdx.x * blockDim.x + threadIdx.x;
  int m = t >> 12;
  int o = t & 4095;
  const int f = g_perm_is64;
  const long long* p64 = (const long long*)perm_raw;
  const int*       p32 = (const int*)perm_raw;
  const float* xr = x + (size_t)m * IN_F;
  const int*   wr = w_q + (size_t)o * IN_F;
  float acc = 0.f;
  for (int g = 0; g < NG; ++g) {
    float part = 0.f;
    for (int k = 0; k < GRP; ++k) {
      int j = g * GRP + k;
      int pj = f ? (int)p64[j] : p32[j];
      part += xr[pj] * (float)wr[j];
    }
    acc += part * s_w[(size_t)g * OUT_F + o];
  }
  out[t] = acc + bias[o];
}

extern "C" void kernel_launch(void* const* d_in, const int* in_sizes, int n_in,
                              void* d_out, int out_size, void* d_ws, size_t ws_size,
                              hipStream_t stream) {
  const float* x    = (const float*)d_in[0];
  const int*   w_q  = (const int*)d_in[1];
  const float* s_w  = (const float*)d_in[2];
  const void*  perm = d_in[3];   // int64 or int32 -- detected on device
  const float* bias = (const float*)d_in[4];
  float* out = (float*)d_out;

  const size_t xq_bytes = (size_t)M_ROWS * IN_F;            // 8 MiB int8
  const size_t w8_bytes = (size_t)OUT_F * IN_F;             // 16 MiB int8
  const size_t sx_bytes = (size_t)M_ROWS * sizeof(float);   // 8 KiB
  const size_t need = xq_bytes + w8_bytes + sx_bytes;

  if (ws_size < need) {
    decode_flag<<<1, 64, 0, stream>>>(perm);
    naive_fallback<<<(M_ROWS * OUT_F) / 256, 256, 0, stream>>>(x, w_q, s_w, perm, bias, out);
    return;
  }

  char*  xq  = (char*)d_ws;
  char*  w8  = (char*)d_ws + xq_bytes;
  float* sxr = (float*)((char*)d_ws + xq_bytes + w8_bytes);

  prep<<<M_ROWS + OUT_F, 256, 0, stream>>>(x, w_q, perm, xq, w8, sxr);

  dim3 grid(OUT_F / 128, M_ROWS / 128);  // 32 x 16 = 512 blocks, 2/CU
  gemm_i8<<<grid, 256, 0, stream>>>(xq, w8, s_w, sxr, bias, out);
}